// Round 5
// baseline (1113.838 us; speedup 1.0000x reference)
//
#include <hip/hip_runtime.h>
#include <hip/hip_bf16.h>

#define BB 64
#define TT 12
#define NN 207
#define DD 128
#define HH 8
#define DH 16
#define MROWS (BB*TT*NN)   // 158976 = 621*256
#define KPAD 224           // graph rows padded to multiple of 32
#define AW 768             // abuf width: [x | xs1 | s0 | t0 | s1 | t1] each 128
#define CHB 32             // batch chunk for qkv/attention
#define CROWS (CHB*TT*NN)  // 79488 rows per chunk

typedef __bf16 bf16x8 __attribute__((ext_vector_type(8)));
typedef float  f32x4  __attribute__((ext_vector_type(4)));

__device__ inline float  b2f(__bf16 v){ return (float)v; }
__device__ inline __bf16 f2b(float v){ return (__bf16)v; }
__device__ inline bf16x8 ldfrag(const __bf16* p){ return *reinterpret_cast<const bf16x8*>(p); }

// ---------------- x (f32) -> abuf[:,0:128] bf16 ----------------
__global__ __launch_bounds__(256) void xcopy_kernel(const float* __restrict__ x, __bf16* __restrict__ abuf)
{
    int nt = gridDim.x*256;
    for (int gIdx = blockIdx.x*256 + threadIdx.x; gIdx < MROWS*16; gIdx += nt) {
        int row = gIdx >> 4, c8 = (gIdx & 15)*8;
        const float* s = x + (size_t)row*DD + c8;
        f32x4 a = *reinterpret_cast<const f32x4*>(s);
        f32x4 b = *reinterpret_cast<const f32x4*>(s+4);
        bf16x8 r;
        #pragma unroll
        for (int i=0;i<4;i++){ r[i] = f2b(a[i]); r[i+4] = f2b(b[i]); }
        *reinterpret_cast<bf16x8*>(abuf + (size_t)row*AW + c8) = r;
    }
}

// ---------------- misc prep: pad graph + convert weights to bf16 + combined bias ----------------
__global__ __launch_bounds__(256) void prep_misc_kernel(
    const float* __restrict__ graph, const float* __restrict__ qkv_w,
    const float* __restrict__ out_w, const float* __restrict__ out_b,
    const float* __restrict__ pw_w,  const float* __restrict__ pw_b,
    const float* __restrict__ fc1_w, const float* __restrict__ fc2_w,
    __bf16* __restrict__ gpad, __bf16* __restrict__ qkv_wb, __bf16* __restrict__ wcomb,
    __bf16* __restrict__ fc1_wb, __bf16* __restrict__ fc2_wb, float* __restrict__ bias_comb)
{
    int nt = gridDim.x*256;
    int tid = blockIdx.x*256 + threadIdx.x;
    for (int i = tid; i < TT*NN*KPAD; i += nt) {
        int k = i % KPAD, r = i / KPAD;
        gpad[i] = (k < NN) ? f2b(graph[(size_t)r*NN + k]) : f2b(0.f);
    }
    for (int i = tid; i < 2*3*DD*DD; i += nt) qkv_wb[i] = f2b(qkv_w[i]);
    for (int i = tid; i < DD*AW; i += nt) {
        int c = i / AW, j = i % AW;
        float v;
        if      (j < 128) v = pw_w[c*128 + j];
        else if (j < 256) v = pw_w[128*128 + c*128 + (j-128)];
        else if (j < 512) v = out_w[c*256 + (j-256)];
        else              v = out_w[128*256 + c*256 + (j-512)];
        wcomb[i] = f2b(v);
    }
    for (int i = tid; i < 2*DD*DD; i += nt) fc1_wb[i] = f2b(fc1_w[i]);
    for (int i = tid; i < 2*DD*DD; i += nt) fc2_wb[i] = f2b(fc2_w[i]);
    for (int i = tid; i < DD; i += nt)
        bias_comb[i] = pw_b[i] + pw_b[128+i] + out_b[i] + out_b[128+i];
}

// ---------------- propagate: abuf[:,128:256] = graph[t] @ abuf[:,0:128]  per (b,t) ----------------
__global__ __launch_bounds__(256) void propagate_kernel(const __bf16* __restrict__ gp,
    __bf16* __restrict__ abuf)
{
    int bt   = blockIdx.x;          // b*12 + t
    int t    = bt % TT;
    int tile = blockIdx.y;          // 0..3, 64 rows each
    int lane = threadIdx.x & 63, w = threadIdx.x >> 6;
    int lhi = lane >> 4, llo = lane & 15;
    __shared__ __attribute__((aligned(16))) __bf16 XT[DD][40];
    const __bf16* xbt  = abuf + (size_t)bt*NN*AW;     // x cols 0:128
    const __bf16* grow = gp + (size_t)t*NN*KPAD;
    int rowbase = tile*64 + w*16;
    f32x4 acc[8];
    #pragma unroll
    for (int i=0;i<8;i++) acc[i] = (f32x4){0.f,0.f,0.f,0.f};
    int arow = rowbase + llo; if (arow > NN-1) arow = NN-1;
    for (int k0=0; k0<KPAD; k0+=32) {
        __syncthreads();
        for (int kl = (threadIdx.x>>7); kl < 32; kl += 2) {
            int kk = k0 + kl, c = threadIdx.x & 127;
            XT[c][kl] = (kk < NN) ? xbt[(size_t)kk*AW + c] : f2b(0.f);
        }
        __syncthreads();
        bf16x8 a = ldfrag(grow + (size_t)arow*KPAD + k0 + lhi*8);
        #pragma unroll
        for (int cf=0;cf<8;cf++){
            bf16x8 b = *reinterpret_cast<const bf16x8*>(&XT[cf*16+llo][lhi*8]);
            acc[cf] = __builtin_amdgcn_mfma_f32_16x16x32_bf16(a, b, acc[cf], 0,0,0);
        }
    }
    #pragma unroll
    for (int e=0;e<4;e++){
        int row = rowbase + lhi*4 + e;
        if (row < NN) {
            #pragma unroll
            for (int cf=0;cf<8;cf++)
                abuf[((size_t)bt*NN + row)*AW + DD + cf*16 + llo] = f2b(acc[cf][e]);
        }
    }
}

// ---------------- generic GEMM, 512 threads / 8 waves, wave = 32 rows x 128 cols ----------------
// A: bf16, row stride lda, rows clamped to mend. W: bf16 [NC][K] dense. grid: (ceil(M/256), NC/128).
// MODE 0: bf16 out (opt RELU).
// MODE 3: out_bf16[row*ldc+col] = LN(resid_bf16[row*ldr+col] + acc + bias) (grid.y==1, NC=128)
// MODE 4: out_f32 [row*ldc+col] = LN(resid_bf16[row*ldr+col] + acc + bias) (grid.y==1, NC=128)
template<int MODE, bool RELU>
__global__ __launch_bounds__(512) void gemm_kernel(const __bf16* __restrict__ A, size_t lda,
    const __bf16* __restrict__ W, const float* __restrict__ bias,
    void* out, size_t ldc, int K, int mend,
    const __bf16* __restrict__ resid, size_t ldr,
    const float* __restrict__ lng, const float* __restrict__ lnb)
{
    int w = threadIdx.x >> 6, lane = threadIdx.x & 63;
    int lhi = lane >> 4, llo = lane & 15;
    size_t row0 = (size_t)blockIdx.x*256 + (size_t)w*32;
    int col0 = blockIdx.y*128;
    const __bf16* aptr[2];
    #pragma unroll
    for (int rt=0;rt<2;rt++){
        long r = (long)(row0 + rt*16 + llo);
        if (r >= mend) r = mend-1;
        aptr[rt] = A + (size_t)r*lda;
    }
    f32x4 acc[2][8];
    #pragma unroll
    for (int i=0;i<2;i++)
        #pragma unroll
        for (int j=0;j<8;j++) acc[i][j] = (f32x4){0.f,0.f,0.f,0.f};
    for (int k0 = 0; k0 < K; k0 += 32) {
        int ke = k0 + lhi*8;
        bf16x8 a[2], b[8];
        #pragma unroll
        for (int rt=0;rt<2;rt++) a[rt] = ldfrag(aptr[rt] + ke);
        #pragma unroll
        for (int cf=0;cf<8;cf++)
            b[cf] = ldfrag(W + (size_t)(col0 + cf*16 + llo)*K + ke);
        #pragma unroll
        for (int rt=0;rt<2;rt++)
            #pragma unroll
            for (int cf=0;cf<8;cf++)
                acc[rt][cf] = __builtin_amdgcn_mfma_f32_16x16x32_bf16(a[rt], b[cf], acc[rt][cf], 0,0,0);
    }
    float bv[8];
    #pragma unroll
    for (int cf=0;cf<8;cf++) bv[cf] = bias ? bias[col0 + cf*16 + llo] : 0.f;

    if (MODE == 0) {
        #pragma unroll
        for (int rt=0;rt<2;rt++) {
            #pragma unroll
            for (int e=0;e<4;e++) {
                size_t row = row0 + rt*16 + lhi*4 + e;
                if ((long)row >= mend) continue;
                #pragma unroll
                for (int cf=0;cf<8;cf++) {
                    float v = acc[rt][cf][e] + bv[cf];
                    if (RELU) v = fmaxf(v, 0.f);
                    ((__bf16*)out)[row*ldc + col0 + cf*16 + llo] = f2b(v);
                }
            }
        }
    } else {
        // fused LayerNorm epilogue (col0 == 0, full 128 cols within wave)
        float g8[8], b8[8];
        #pragma unroll
        for (int cf=0;cf<8;cf++){ int c = cf*16 + llo; g8[cf] = lng[c]; b8[cf] = lnb[c]; }
        #pragma unroll
        for (int rt=0;rt<2;rt++) {
            #pragma unroll
            for (int e=0;e<4;e++) {
                size_t row = row0 + rt*16 + lhi*4 + e;
                if ((long)row >= mend) continue;
                float vals[8], s = 0.f, ss = 0.f;
                #pragma unroll
                for (int cf=0;cf<8;cf++) {
                    int c = cf*16 + llo;
                    float r = b2f(resid[row*ldr + c]);
                    float v = acc[rt][cf][e] + bv[cf] + r;
                    vals[cf] = v; s += v; ss += v*v;
                }
                #pragma unroll
                for (int o=1;o<16;o<<=1){ s += __shfl_xor(s,o,64); ss += __shfl_xor(ss,o,64); }
                float mean = s * (1.f/DD);
                float var  = ss * (1.f/DD) - mean*mean;
                float rs   = rsqrtf(var + 1e-5f);
                #pragma unroll
                for (int cf=0;cf<8;cf++) {
                    float v = (vals[cf]-mean)*rs*g8[cf] + b8[cf];
                    size_t idx = row*ldc + cf*16 + llo;
                    if (MODE == 3) ((__bf16*)out)[idx] = f2b(v);
                    else           ((float*)out)[idx]  = v;
                }
            }
        }
    }
}

// ---------------- spatial linear attention: one block per chunk-(b,t), all 8 heads ----------------
#define CH 32
__global__ __launch_bounds__(256) void attn_s_kernel(const __bf16* __restrict__ qkv,
                                                     __bf16* __restrict__ outp)
{
    int bt = blockIdx.x;   // chunk-local
    const __bf16* base = qkv + (size_t)bt*NN*384;
    __shared__ __attribute__((aligned(16))) __bf16 rows[CH][392];
    __shared__ float invq[224][8];
    __shared__ float invk_c[CH][8];
    __shared__ float ksum_l[8][16];
    int tid = threadIdx.x;
    int dd = tid & 15, half = (tid >> 4) & 1, h = tid >> 5;
    float kvs_col[16]; float ks = 0.f;
    #pragma unroll
    for (int m=0;m<16;m++) kvs_col[m] = 0.f;

    for (int c0 = 0; c0 < NN; c0 += CH) {
        __syncthreads();
        for (int i = tid; i < CH*48; i += 256) {
            int r = i/48, g = i%48; int n = c0 + r;
            bf16x8 v8 = (bf16x8){};
            if (n < NN) v8 = *reinterpret_cast<const bf16x8*>(base + (size_t)n*384 + g*8);
            *reinterpret_cast<bf16x8*>(&rows[r][g*8]) = v8;
        }
        __syncthreads();
        {
            int r = tid >> 3, hh = tid & 7;
            bf16x8 q0 = *reinterpret_cast<const bf16x8*>(&rows[r][hh*16]);
            bf16x8 q1 = *reinterpret_cast<const bf16x8*>(&rows[r][hh*16+8]);
            bf16x8 k0 = *reinterpret_cast<const bf16x8*>(&rows[r][128+hh*16]);
            bf16x8 k1 = *reinterpret_cast<const bf16x8*>(&rows[r][128+hh*16+8]);
            float sq = 0.f, sk = 0.f;
            #pragma unroll
            for (int m=0;m<8;m++){
                float a0=b2f(q0[m]), a1=b2f(q1[m]); sq += a0*a0 + a1*a1;
                float c0v=b2f(k0[m]), c1=b2f(k1[m]); sk += c0v*c0v + c1*c1;
            }
            invq[c0+r][hh] = 1.f/fmaxf(sqrtf(sq), 1e-12f);
            invk_c[r][hh]  = 1.f/fmaxf(sqrtf(sk), 1e-12f);
        }
        __syncthreads();
        #pragma unroll
        for (int i=0;i<CH/2;i++){
            int r = half*(CH/2) + i;
            float iv = invk_c[r][h];
            bf16x8 k0 = *reinterpret_cast<const bf16x8*>(&rows[r][128+h*16]);
            bf16x8 k1 = *reinterpret_cast<const bf16x8*>(&rows[r][128+h*16+8]);
            float vv  = b2f(rows[r][256+h*16+dd]);
            float kdd = b2f(rows[r][128+h*16+dd]);
            float t2 = iv*vv;
            #pragma unroll
            for (int m=0;m<8;m++){
                kvs_col[m]   += b2f(k0[m])*t2;
                kvs_col[m+8] += b2f(k1[m])*t2;
            }
            ks += kdd*iv;
        }
    }
    #pragma unroll
    for (int m=0;m<16;m++) kvs_col[m] += __shfl_xor(kvs_col[m], 16, 64);
    ks += __shfl_xor(ks, 16, 64);
    ksum_l[h][dd] = ks;
    __syncthreads();
    float ksr[16];
    #pragma unroll
    for (int m=0;m<16;m++) ksr[m] = ksum_l[h][m];

    for (int c0 = 0; c0 < NN; c0 += CH) {
        __syncthreads();
        for (int i = tid; i < CH*48; i += 256) {
            int r = i/48, g = i%48; int n = c0 + r;
            bf16x8 v8 = (bf16x8){};
            if (n < NN) v8 = *reinterpret_cast<const bf16x8*>(base + (size_t)n*384 + g*8);
            *reinterpret_cast<bf16x8*>(&rows[r][g*8]) = v8;
        }
        __syncthreads();
        #pragma unroll
        for (int i=0;i<CH/2;i++){
            int r = half*(CH/2) + i; int n = c0 + r;
            if (n >= NN) continue;
            float iq = invq[n][h];
            bf16x8 q0 = *reinterpret_cast<const bf16x8*>(&rows[r][h*16]);
            bf16x8 q1 = *reinterpret_cast<const bf16x8*>(&rows[r][h*16+8]);
            float num = 0.f, den = 0.f;
            #pragma unroll
            for (int m=0;m<8;m++){
                float qm0 = b2f(q0[m]), qm1 = b2f(q1[m]);
                num += qm0*kvs_col[m] + qm1*kvs_col[m+8];
                den += qm0*ksr[m]     + qm1*ksr[m+8];
            }
            float vv = b2f(rows[r][256+h*16+dd]);
            float o = (num*iq + (float)NN*vv) / fmaxf(den*iq + (float)NN, 1e-5f);
            outp[((size_t)bt*NN + n)*AW + h*16 + dd] = f2b(o);
        }
    }
}

// ---------------- temporal linear attention: one block per chunk-(b, nn-pair) ----------------
__global__ __launch_bounds__(256) void attn_t_kernel(const __bf16* __restrict__ qkv,
                                                     __bf16* __restrict__ outp)
{
    int b = blockIdx.x;    // chunk-local
    int nn0 = blockIdx.y * 2;
    __shared__ __attribute__((aligned(16))) __bf16 rows[TT][2][384];
    __shared__ float invq[2][TT][8], invk2[2][TT][8];
    int tid = threadIdx.x;
    for (int i = tid; i < TT*2*48; i += 256) {
        int t = i / 96, rem = i % 96;
        int nl = rem / 48, g = rem % 48;
        int nn = nn0 + nl;
        bf16x8 v8 = (bf16x8){};
        if (nn < NN) v8 = *reinterpret_cast<const bf16x8*>(qkv + ((size_t)(b*TT+t)*NN + nn)*384 + g*8);
        *reinterpret_cast<bf16x8*>(&rows[t][nl][g*8]) = v8;
    }
    __syncthreads();
    if (tid < 192) {
        int hh = tid & 7, t = (tid >> 3) % TT, nl = tid / 96;
        bf16x8 q0 = *reinterpret_cast<const bf16x8*>(&rows[t][nl][hh*16]);
        bf16x8 q1 = *reinterpret_cast<const bf16x8*>(&rows[t][nl][hh*16+8]);
        bf16x8 k0 = *reinterpret_cast<const bf16x8*>(&rows[t][nl][128+hh*16]);
        bf16x8 k1 = *reinterpret_cast<const bf16x8*>(&rows[t][nl][128+hh*16+8]);
        float sq = 0.f, sk = 0.f;
        #pragma unroll
        for (int m=0;m<8;m++){
            float a0=b2f(q0[m]), a1=b2f(q1[m]); sq += a0*a0 + a1*a1;
            float c0v=b2f(k0[m]), c1=b2f(k1[m]); sk += c0v*c0v + c1*c1;
        }
        invq[nl][t][hh]  = 1.f/fmaxf(sqrtf(sq), 1e-12f);
        invk2[nl][t][hh] = 1.f/fmaxf(sqrtf(sk), 1e-12f);
    }
    __syncthreads();
    int dd = tid & 15, h = (tid >> 4) & 7, nl = tid >> 7;
    int nn = nn0 + nl;
    float kvs_col[16], ksum[16];
    #pragma unroll
    for (int m=0;m<16;m++){ kvs_col[m]=0.f; ksum[m]=0.f; }
    #pragma unroll
    for (int t=0;t<TT;t++){
        float iv = invk2[nl][t][h];
        bf16x8 k0 = *reinterpret_cast<const bf16x8*>(&rows[t][nl][128+h*16]);
        bf16x8 k1 = *reinterpret_cast<const bf16x8*>(&rows[t][nl][128+h*16+8]);
        float vv = b2f(rows[t][nl][256+h*16+dd]);
        float t2 = iv*vv;
        #pragma unroll
        for (int m=0;m<8;m++){
            float km0 = b2f(k0[m]), km1 = b2f(k1[m]);
            kvs_col[m]   += km0*t2;  ksum[m]   += km0*iv;
            kvs_col[m+8] += km1*t2;  ksum[m+8] += km1*iv;
        }
    }
    #pragma unroll
    for (int t=0;t<TT;t++){
        float iq = invq[nl][t][h];
        bf16x8 q0 = *reinterpret_cast<const bf16x8*>(&rows[t][nl][h*16]);
        bf16x8 q1 = *reinterpret_cast<const bf16x8*>(&rows[t][nl][h*16+8]);
        float num = 0.f, den = 0.f;
        #pragma unroll
        for (int m=0;m<8;m++){
            float qm0 = b2f(q0[m]), qm1 = b2f(q1[m]);
            num += qm0*kvs_col[m]  + qm1*kvs_col[m+8];
            den += qm0*ksum[m]     + qm1*ksum[m+8];
        }
        float vv = b2f(rows[t][nl][256+h*16+dd]);
        float o = (num*iq + (float)TT*vv) / fmaxf(den*iq + (float)TT, 1e-5f);
        if (nn < NN)
            outp[((size_t)(b*TT+t)*NN + nn)*AW + h*16 + dd] = f2b(o);
    }
}

extern "C" void kernel_launch(void* const* d_in, const int* in_sizes, int n_in,
                              void* d_out, int out_size, void* d_ws, size_t ws_size,
                              hipStream_t stream)
{
    const float* x     = (const float*)d_in[0];
    const float* graph = (const float*)d_in[1];
    const float* qkv_w = (const float*)d_in[2];
    const float* out_w = (const float*)d_in[3];
    const float* out_b = (const float*)d_in[4];
    const float* pw_w  = (const float*)d_in[5];
    const float* pw_b  = (const float*)d_in[6];
    const float* fc1_w = (const float*)d_in[7];
    const float* fc1_b = (const float*)d_in[8];
    const float* fc2_w = (const float*)d_in[9];
    const float* fc2_b = (const float*)d_in[10];
    const float* ln1g  = (const float*)d_in[11];
    const float* ln1b  = (const float*)d_in[12];
    const float* ln2g  = (const float*)d_in[13];
    const float* ln2b  = (const float*)d_in[14];
    (void)in_sizes; (void)n_in; (void)out_size; (void)ws_size;

    char* ws = (char*)d_ws;
    size_t off = 0;
    __bf16* abuf = (__bf16*)(ws + off); off += (size_t)MROWS*AW*2;      // 244.2 MB
    __bf16* qkvc = (__bf16*)(ws + off); off += (size_t)CROWS*3*DD*2;    // 61.0 MB
    __bf16* gpad = (__bf16*)(ws + off); off += (size_t)TT*NN*KPAD*2;    // 1.1 MB
    __bf16* qkv_wb = (__bf16*)(ws + off); off += (size_t)2*3*DD*DD*2;
    __bf16* wcomb  = (__bf16*)(ws + off); off += (size_t)DD*AW*2;
    __bf16* fc1_wb = (__bf16*)(ws + off); off += (size_t)2*DD*DD*2;
    __bf16* fc2_wb = (__bf16*)(ws + off); off += (size_t)2*DD*DD*2;
    float*  bias_comb = (float*)(ws + off); off += DD*4;                // total ~293 MB

    dim3 blk(256), blk512(512);

    xcopy_kernel<<<dim3(4096), blk, 0, stream>>>(x, abuf);
    prep_misc_kernel<<<dim3(1024), blk, 0, stream>>>(graph, qkv_w, out_w, out_b, pw_w, pw_b,
        fc1_w, fc2_w, gpad, qkv_wb, wcomb, fc1_wb, fc2_wb, bias_comb);
    propagate_kernel<<<dim3(BB*TT, 4), blk, 0, stream>>>(gpad, abuf);

    for (int hop = 0; hop < 2; ++hop) {
        for (int c = 0; c < BB/CHB; ++c) {
            size_t rowoff = (size_t)c*CROWS;
            gemm_kernel<0,false><<<dim3((CROWS+255)/256, 3), blk512, 0, stream>>>(
                abuf + rowoff*AW + hop*DD, (size_t)AW, qkv_wb + (size_t)hop*3*DD*DD, nullptr,
                (void*)qkvc, (size_t)(3*DD), DD, CROWS, nullptr, 0, nullptr, nullptr);
            attn_s_kernel<<<dim3(CHB*TT), blk, 0, stream>>>(
                qkvc, abuf + rowoff*AW + 256 + hop*256);
            attn_t_kernel<<<dim3(CHB, (NN+1)/2), blk, 0, stream>>>(
                qkvc, abuf + rowoff*AW + 384 + hop*256);
        }
    }

    // h = LN(x + abuf@wcomb^T + bias_comb) -> abuf cols 0:128 (bf16), fused epilogue
    // residual read from abuf cols 0:128 (bf16 copy of x, same cache lines as A)
    gemm_kernel<3,false><<<dim3(MROWS/256, 1), blk512, 0, stream>>>(
        abuf, (size_t)AW, wcomb, bias_comb, (void*)abuf, (size_t)AW, AW, MROWS,
        abuf, (size_t)AW, ln1g, ln1b);
    // ff1 = relu(h @ fc1^T + b1) -> abuf cols 256:512
    gemm_kernel<0,true><<<dim3(MROWS/256, 2), blk512, 0, stream>>>(
        abuf, (size_t)AW, fc1_wb, fc1_b, (void*)(abuf + 256), (size_t)AW, DD, MROWS,
        nullptr, 0, nullptr, nullptr);
    // out = LN(h + ff1 @ fc2^T + b2) -> d_out f32, fused epilogue
    gemm_kernel<4,false><<<dim3(MROWS/256, 1), blk512, 0, stream>>>(
        abuf + 256, (size_t)AW, fc2_wb, fc2_b, d_out, (size_t)DD, 2*DD, MROWS,
        abuf, (size_t)AW, ln2g, ln2b);
}

// Round 6
// 863.749 us; speedup vs baseline: 1.2895x; 1.2895x over previous
//
#include <hip/hip_runtime.h>
#include <hip/hip_bf16.h>

#define BB 64
#define TT 12
#define NN 207
#define DD 128
#define HH 8
#define DH 16
#define MROWS (BB*TT*NN)   // 158976 = 621*256
#define KPAD 224           // graph rows padded to multiple of 32
#define AW 768             // abuf width: [x | xs1 | s0 | t0 | s1 | t1] each 128
#define CHB 32             // batch chunk for qkv/attention
#define CROWS (CHB*TT*NN)  // 79488 rows per chunk

typedef __bf16 bf16x8 __attribute__((ext_vector_type(8)));
typedef float  f32x4  __attribute__((ext_vector_type(4)));

__device__ inline float  b2f(__bf16 v){ return (float)v; }
__device__ inline __bf16 f2b(float v){ return (__bf16)v; }
__device__ inline bf16x8 ldfrag(const __bf16* p){ return *reinterpret_cast<const bf16x8*>(p); }

// async global->LDS, 16B per lane; lds base must be wave-uniform (lane i lands at +16*i)
__device__ inline void gload_lds16(const __bf16* g, __bf16* l){
    __builtin_amdgcn_global_load_lds(
        (const __attribute__((address_space(1))) void*)(g),
        (__attribute__((address_space(3))) void*)(l), 16, 0, 0);
}
__device__ inline int swz(int r){ return (r ^ (r>>2)) & 3; }

// ---------------- x (f32) -> abuf[:,0:128] bf16 ----------------
__global__ __launch_bounds__(256) void xcopy_kernel(const float* __restrict__ x, __bf16* __restrict__ abuf)
{
    int nt = gridDim.x*256;
    for (int gIdx = blockIdx.x*256 + threadIdx.x; gIdx < MROWS*16; gIdx += nt) {
        int row = gIdx >> 4, c8 = (gIdx & 15)*8;
        const float* s = x + (size_t)row*DD + c8;
        f32x4 a = *reinterpret_cast<const f32x4*>(s);
        f32x4 b = *reinterpret_cast<const f32x4*>(s+4);
        bf16x8 r;
        #pragma unroll
        for (int i=0;i<4;i++){ r[i] = f2b(a[i]); r[i+4] = f2b(b[i]); }
        *reinterpret_cast<bf16x8*>(abuf + (size_t)row*AW + c8) = r;
    }
}

// ---------------- misc prep: pad graph + convert weights to bf16 + combined bias ----------------
__global__ __launch_bounds__(256) void prep_misc_kernel(
    const float* __restrict__ graph, const float* __restrict__ qkv_w,
    const float* __restrict__ out_w, const float* __restrict__ out_b,
    const float* __restrict__ pw_w,  const float* __restrict__ pw_b,
    const float* __restrict__ fc1_w, const float* __restrict__ fc2_w,
    __bf16* __restrict__ gpad, __bf16* __restrict__ qkv_wb, __bf16* __restrict__ wcomb,
    __bf16* __restrict__ fc1_wb, __bf16* __restrict__ fc2_wb, float* __restrict__ bias_comb)
{
    int nt = gridDim.x*256;
    int tid = blockIdx.x*256 + threadIdx.x;
    for (int i = tid; i < TT*NN*KPAD; i += nt) {
        int k = i % KPAD, r = i / KPAD;
        gpad[i] = (k < NN) ? f2b(graph[(size_t)r*NN + k]) : f2b(0.f);
    }
    for (int i = tid; i < 2*3*DD*DD; i += nt) qkv_wb[i] = f2b(qkv_w[i]);
    for (int i = tid; i < DD*AW; i += nt) {
        int c = i / AW, j = i % AW;
        float v;
        if      (j < 128) v = pw_w[c*128 + j];
        else if (j < 256) v = pw_w[128*128 + c*128 + (j-128)];
        else if (j < 512) v = out_w[c*256 + (j-256)];
        else              v = out_w[128*256 + c*256 + (j-512)];
        wcomb[i] = f2b(v);
    }
    for (int i = tid; i < 2*DD*DD; i += nt) fc1_wb[i] = f2b(fc1_w[i]);
    for (int i = tid; i < 2*DD*DD; i += nt) fc2_wb[i] = f2b(fc2_w[i]);
    for (int i = tid; i < DD; i += nt)
        bias_comb[i] = pw_b[i] + pw_b[128+i] + out_b[i] + out_b[128+i];
}

// ---------------- propagate: abuf[:,128:256] = graph[t] @ abuf[:,0:128]  per (b,t) ----------------
__global__ __launch_bounds__(256) void propagate_kernel(const __bf16* __restrict__ gp,
    __bf16* __restrict__ abuf)
{
    int bt   = blockIdx.x;          // b*12 + t
    int t    = bt % TT;
    int tile = blockIdx.y;          // 0..3, 64 rows each
    int lane = threadIdx.x & 63, w = threadIdx.x >> 6;
    int lhi = lane >> 4, llo = lane & 15;
    __shared__ __attribute__((aligned(16))) __bf16 XT[DD][40];
    const __bf16* xbt  = abuf + (size_t)bt*NN*AW;     // x cols 0:128
    const __bf16* grow = gp + (size_t)t*NN*KPAD;
    int rowbase = tile*64 + w*16;
    f32x4 acc[8];
    #pragma unroll
    for (int i=0;i<8;i++) acc[i] = (f32x4){0.f,0.f,0.f,0.f};
    int arow = rowbase + llo; if (arow > NN-1) arow = NN-1;
    for (int k0=0; k0<KPAD; k0+=32) {
        __syncthreads();
        for (int kl = (threadIdx.x>>7); kl < 32; kl += 2) {
            int kk = k0 + kl, c = threadIdx.x & 127;
            XT[c][kl] = (kk < NN) ? xbt[(size_t)kk*AW + c] : f2b(0.f);
        }
        __syncthreads();
        bf16x8 a = ldfrag(grow + (size_t)arow*KPAD + k0 + lhi*8);
        #pragma unroll
        for (int cf=0;cf<8;cf++){
            bf16x8 b = *reinterpret_cast<const bf16x8*>(&XT[cf*16+llo][lhi*8]);
            acc[cf] = __builtin_amdgcn_mfma_f32_16x16x32_bf16(a, b, acc[cf], 0,0,0);
        }
    }
    #pragma unroll
    for (int e=0;e<4;e++){
        int row = rowbase + lhi*4 + e;
        if (row < NN) {
            #pragma unroll
            for (int cf=0;cf<8;cf++)
                abuf[((size_t)bt*NN + row)*AW + DD + cf*16 + llo] = f2b(acc[cf][e]);
        }
    }
}

// ---------------- LDS-staged GEMM, 512 threads / 8 waves, block = 256 rows x 128 cols ----------------
// BK=32 double-buffered via global_load_lds; A-tile [256][32], W-tile [128][32], both
// stored with 16B-unit swizzle u^=swz(r) (pre-swizzled global source, swizzled ds_read).
// MODE 0: bf16 out (opt RELU).
// MODE 3: out_bf16[row*ldc+col] = LN(resid_bf16[row*ldr+col] + acc + bias) (grid.y==1, NC=128)
// MODE 4: out_f32 [row*ldc+col] = LN(resid_bf16[row*ldr+col] + acc + bias) (grid.y==1, NC=128)
template<int MODE, bool RELU>
__global__ __launch_bounds__(512) void gemm_kernel(const __bf16* __restrict__ A, size_t lda,
    const __bf16* __restrict__ W, const float* __restrict__ bias,
    void* out, size_t ldc, int K, int mend,
    const __bf16* __restrict__ resid, size_t ldr,
    const float* __restrict__ lng, const float* __restrict__ lnb)
{
    __shared__ __attribute__((aligned(16))) __bf16 lds[2][12288]; // 2 x (A 8192 | W 4096) = 48KB
    int w = threadIdx.x >> 6, lane = threadIdx.x & 63;
    int lhi = lane >> 4, llo = lane & 15;
    size_t row0 = (size_t)blockIdx.x*256;
    int col0 = blockIdx.y*128;
    int nt = K >> 5;

    // staging slot constants (per thread)
    int sA0 = (w*2+0)*64 + lane, sA1 = (w*2+1)*64 + lane, sW = w*64 + lane;
    int rA0 = sA0>>2, uA0 = sA0&3, rA1 = sA1>>2, uA1 = sA1&3, rW = sW>>2, uW = sW&3;
    long gr0 = (long)row0 + rA0; if (gr0 >= mend) gr0 = mend-1;
    long gr1 = (long)row0 + rA1; if (gr1 >= mend) gr1 = mend-1;
    const __bf16* gA0 = A + (size_t)gr0*lda + ((uA0 ^ swz(rA0))<<3);
    const __bf16* gA1 = A + (size_t)gr1*lda + ((uA1 ^ swz(rA1))<<3);
    const __bf16* gW  = W + (size_t)(col0 + rW)*K + ((uW ^ swz(rW))<<3);
    __bf16* dA0base[2] = { &lds[0][(w*2+0)*512], &lds[1][(w*2+0)*512] };
    __bf16* dA1base[2] = { &lds[0][(w*2+1)*512], &lds[1][(w*2+1)*512] };
    __bf16* dWbase[2]  = { &lds[0][8192 + w*512], &lds[1][8192 + w*512] };

    // fragment read offsets (per thread)
    int aoff[2], woff[8];
    #pragma unroll
    for (int rt=0;rt<2;rt++){
        int rl = w*32 + rt*16 + llo;
        aoff[rt] = rl*32 + ((lhi ^ swz(rl))<<3);
    }
    #pragma unroll
    for (int cf=0;cf<8;cf++){
        int wr = cf*16 + llo;
        woff[cf] = 8192 + wr*32 + ((lhi ^ swz(wr))<<3);
    }

    f32x4 acc[2][8];
    #pragma unroll
    for (int i=0;i<2;i++)
        #pragma unroll
        for (int j=0;j<8;j++) acc[i][j] = (f32x4){0.f,0.f,0.f,0.f};

    // prologue: stage chunk 0
    gload_lds16(gA0, dA0base[0]);
    gload_lds16(gA1, dA1base[0]);
    gload_lds16(gW,  dWbase[0]);
    __syncthreads();

    for (int t = 0; t < nt; ++t) {
        int cur = t & 1;
        if (t+1 < nt) {
            int k0 = (t+1) << 5;
            gload_lds16(gA0 + k0, dA0base[cur^1]);
            gload_lds16(gA1 + k0, dA1base[cur^1]);
            gload_lds16(gW  + k0, dWbase[cur^1]);
        }
        const __bf16* Lb = lds[cur];
        bf16x8 a[2], b[8];
        #pragma unroll
        for (int rt=0;rt<2;rt++) a[rt] = *reinterpret_cast<const bf16x8*>(&Lb[aoff[rt]]);
        #pragma unroll
        for (int cf=0;cf<8;cf++)  b[cf] = *reinterpret_cast<const bf16x8*>(&Lb[woff[cf]]);
        #pragma unroll
        for (int rt=0;rt<2;rt++)
            #pragma unroll
            for (int cf=0;cf<8;cf++)
                acc[rt][cf] = __builtin_amdgcn_mfma_f32_16x16x32_bf16(a[rt], b[cf], acc[rt][cf], 0,0,0);
        __syncthreads();
    }

    float bv[8];
    #pragma unroll
    for (int cf=0;cf<8;cf++) bv[cf] = bias ? bias[col0 + cf*16 + llo] : 0.f;

    if (MODE == 0) {
        #pragma unroll
        for (int rt=0;rt<2;rt++) {
            #pragma unroll
            for (int e=0;e<4;e++) {
                size_t row = row0 + (size_t)w*32 + rt*16 + lhi*4 + e;
                if ((long)row >= mend) continue;
                #pragma unroll
                for (int cf=0;cf<8;cf++) {
                    float v = acc[rt][cf][e] + bv[cf];
                    if (RELU) v = fmaxf(v, 0.f);
                    ((__bf16*)out)[row*ldc + col0 + cf*16 + llo] = f2b(v);
                }
            }
        }
    } else {
        float g8[8], b8[8];
        #pragma unroll
        for (int cf=0;cf<8;cf++){ int c = cf*16 + llo; g8[cf] = lng[c]; b8[cf] = lnb[c]; }
        #pragma unroll
        for (int rt=0;rt<2;rt++) {
            #pragma unroll
            for (int e=0;e<4;e++) {
                size_t row = row0 + (size_t)w*32 + rt*16 + lhi*4 + e;
                if ((long)row >= mend) continue;
                float vals[8], s = 0.f, ss = 0.f;
                #pragma unroll
                for (int cf=0;cf<8;cf++) {
                    int c = cf*16 + llo;
                    float r = b2f(resid[row*ldr + c]);
                    float v = acc[rt][cf][e] + bv[cf] + r;
                    vals[cf] = v; s += v; ss += v*v;
                }
                #pragma unroll
                for (int o=1;o<16;o<<=1){ s += __shfl_xor(s,o,64); ss += __shfl_xor(ss,o,64); }
                float mean = s * (1.f/DD);
                float var  = ss * (1.f/DD) - mean*mean;
                float rs   = rsqrtf(var + 1e-5f);
                #pragma unroll
                for (int cf=0;cf<8;cf++) {
                    float v = (vals[cf]-mean)*rs*g8[cf] + b8[cf];
                    size_t idx = row*ldc + cf*16 + llo;
                    if (MODE == 3) ((__bf16*)out)[idx] = f2b(v);
                    else           ((float*)out)[idx]  = v;
                }
            }
        }
    }
}

// ---------------- spatial linear attention: one block per chunk-(b,t), all 8 heads ----------------
#define CH 32
__global__ __launch_bounds__(256) void attn_s_kernel(const __bf16* __restrict__ qkv,
                                                     __bf16* __restrict__ outp)
{
    int bt = blockIdx.x;   // chunk-local
    const __bf16* base = qkv + (size_t)bt*NN*384;
    __shared__ __attribute__((aligned(16))) __bf16 rows[CH][392];
    __shared__ float invq[224][8];
    __shared__ float invk_c[CH][8];
    __shared__ float ksum_l[8][16];
    int tid = threadIdx.x;
    int dd = tid & 15, half = (tid >> 4) & 1, h = tid >> 5;
    float kvs_col[16]; float ks = 0.f;
    #pragma unroll
    for (int m=0;m<16;m++) kvs_col[m] = 0.f;

    for (int c0 = 0; c0 < NN; c0 += CH) {
        __syncthreads();
        for (int i = tid; i < CH*48; i += 256) {
            int r = i/48, g = i%48; int n = c0 + r;
            bf16x8 v8 = (bf16x8){};
            if (n < NN) v8 = *reinterpret_cast<const bf16x8*>(base + (size_t)n*384 + g*8);
            *reinterpret_cast<bf16x8*>(&rows[r][g*8]) = v8;
        }
        __syncthreads();
        {
            int r = tid >> 3, hh = tid & 7;
            bf16x8 q0 = *reinterpret_cast<const bf16x8*>(&rows[r][hh*16]);
            bf16x8 q1 = *reinterpret_cast<const bf16x8*>(&rows[r][hh*16+8]);
            bf16x8 k0 = *reinterpret_cast<const bf16x8*>(&rows[r][128+hh*16]);
            bf16x8 k1 = *reinterpret_cast<const bf16x8*>(&rows[r][128+hh*16+8]);
            float sq = 0.f, sk = 0.f;
            #pragma unroll
            for (int m=0;m<8;m++){
                float a0=b2f(q0[m]), a1=b2f(q1[m]); sq += a0*a0 + a1*a1;
                float c0v=b2f(k0[m]), c1=b2f(k1[m]); sk += c0v*c0v + c1*c1;
            }
            invq[c0+r][hh] = 1.f/fmaxf(sqrtf(sq), 1e-12f);
            invk_c[r][hh]  = 1.f/fmaxf(sqrtf(sk), 1e-12f);
        }
        __syncthreads();
        #pragma unroll
        for (int i=0;i<CH/2;i++){
            int r = half*(CH/2) + i;
            float iv = invk_c[r][h];
            bf16x8 k0 = *reinterpret_cast<const bf16x8*>(&rows[r][128+h*16]);
            bf16x8 k1 = *reinterpret_cast<const bf16x8*>(&rows[r][128+h*16+8]);
            float vv  = b2f(rows[r][256+h*16+dd]);
            float kdd = b2f(rows[r][128+h*16+dd]);
            float t2 = iv*vv;
            #pragma unroll
            for (int m=0;m<8;m++){
                kvs_col[m]   += b2f(k0[m])*t2;
                kvs_col[m+8] += b2f(k1[m])*t2;
            }
            ks += kdd*iv;
        }
    }
    #pragma unroll
    for (int m=0;m<16;m++) kvs_col[m] += __shfl_xor(kvs_col[m], 16, 64);
    ks += __shfl_xor(ks, 16, 64);
    ksum_l[h][dd] = ks;
    __syncthreads();
    float ksr[16];
    #pragma unroll
    for (int m=0;m<16;m++) ksr[m] = ksum_l[h][m];

    for (int c0 = 0; c0 < NN; c0 += CH) {
        __syncthreads();
        for (int i = tid; i < CH*48; i += 256) {
            int r = i/48, g = i%48; int n = c0 + r;
            bf16x8 v8 = (bf16x8){};
            if (n < NN) v8 = *reinterpret_cast<const bf16x8*>(base + (size_t)n*384 + g*8);
            *reinterpret_cast<bf16x8*>(&rows[r][g*8]) = v8;
        }
        __syncthreads();
        #pragma unroll
        for (int i=0;i<CH/2;i++){
            int r = half*(CH/2) + i; int n = c0 + r;
            if (n >= NN) continue;
            float iq = invq[n][h];
            bf16x8 q0 = *reinterpret_cast<const bf16x8*>(&rows[r][h*16]);
            bf16x8 q1 = *reinterpret_cast<const bf16x8*>(&rows[r][h*16+8]);
            float num = 0.f, den = 0.f;
            #pragma unroll
            for (int m=0;m<8;m++){
                float qm0 = b2f(q0[m]), qm1 = b2f(q1[m]);
                num += qm0*kvs_col[m] + qm1*kvs_col[m+8];
                den += qm0*ksr[m]     + qm1*ksr[m+8];
            }
            float vv = b2f(rows[r][256+h*16+dd]);
            float o = (num*iq + (float)NN*vv) / fmaxf(den*iq + (float)NN, 1e-5f);
            outp[((size_t)bt*NN + n)*AW + h*16 + dd] = f2b(o);
        }
    }
}

// ---------------- temporal linear attention: one block per chunk-(b, nn-pair) ----------------
__global__ __launch_bounds__(256) void attn_t_kernel(const __bf16* __restrict__ qkv,
                                                     __bf16* __restrict__ outp)
{
    int b = blockIdx.x;    // chunk-local
    int nn0 = blockIdx.y * 2;
    __shared__ __attribute__((aligned(16))) __bf16 rows[TT][2][384];
    __shared__ float invq[2][TT][8], invk2[2][TT][8];
    int tid = threadIdx.x;
    for (int i = tid; i < TT*2*48; i += 256) {
        int t = i / 96, rem = i % 96;
        int nl = rem / 48, g = rem % 48;
        int nn = nn0 + nl;
        bf16x8 v8 = (bf16x8){};
        if (nn < NN) v8 = *reinterpret_cast<const bf16x8*>(qkv + ((size_t)(b*TT+t)*NN + nn)*384 + g*8);
        *reinterpret_cast<bf16x8*>(&rows[t][nl][g*8]) = v8;
    }
    __syncthreads();
    if (tid < 192) {
        int hh = tid & 7, t = (tid >> 3) % TT, nl = tid / 96;
        bf16x8 q0 = *reinterpret_cast<const bf16x8*>(&rows[t][nl][hh*16]);
        bf16x8 q1 = *reinterpret_cast<const bf16x8*>(&rows[t][nl][hh*16+8]);
        bf16x8 k0 = *reinterpret_cast<const bf16x8*>(&rows[t][nl][128+hh*16]);
        bf16x8 k1 = *reinterpret_cast<const bf16x8*>(&rows[t][nl][128+hh*16+8]);
        float sq = 0.f, sk = 0.f;
        #pragma unroll
        for (int m=0;m<8;m++){
            float a0=b2f(q0[m]), a1=b2f(q1[m]); sq += a0*a0 + a1*a1;
            float c0v=b2f(k0[m]), c1=b2f(k1[m]); sk += c0v*c0v + c1*c1;
        }
        invq[nl][t][hh]  = 1.f/fmaxf(sqrtf(sq), 1e-12f);
        invk2[nl][t][hh] = 1.f/fmaxf(sqrtf(sk), 1e-12f);
    }
    __syncthreads();
    int dd = tid & 15, h = (tid >> 4) & 7, nl = tid >> 7;
    int nn = nn0 + nl;
    float kvs_col[16], ksum[16];
    #pragma unroll
    for (int m=0;m<16;m++){ kvs_col[m]=0.f; ksum[m]=0.f; }
    #pragma unroll
    for (int t=0;t<TT;t++){
        float iv = invk2[nl][t][h];
        bf16x8 k0 = *reinterpret_cast<const bf16x8*>(&rows[t][nl][128+h*16]);
        bf16x8 k1 = *reinterpret_cast<const bf16x8*>(&rows[t][nl][128+h*16+8]);
        float vv = b2f(rows[t][nl][256+h*16+dd]);
        float t2 = iv*vv;
        #pragma unroll
        for (int m=0;m<8;m++){
            float km0 = b2f(k0[m]), km1 = b2f(k1[m]);
            kvs_col[m]   += km0*t2;  ksum[m]   += km0*iv;
            kvs_col[m+8] += km1*t2;  ksum[m+8] += km1*iv;
        }
    }
    #pragma unroll
    for (int t=0;t<TT;t++){
        float iq = invq[nl][t][h];
        bf16x8 q0 = *reinterpret_cast<const bf16x8*>(&rows[t][nl][h*16]);
        bf16x8 q1 = *reinterpret_cast<const bf16x8*>(&rows[t][nl][h*16+8]);
        float num = 0.f, den = 0.f;
        #pragma unroll
        for (int m=0;m<8;m++){
            float qm0 = b2f(q0[m]), qm1 = b2f(q1[m]);
            num += qm0*kvs_col[m]  + qm1*kvs_col[m+8];
            den += qm0*ksum[m]     + qm1*ksum[m+8];
        }
        float vv = b2f(rows[t][nl][256+h*16+dd]);
        float o = (num*iq + (float)TT*vv) / fmaxf(den*iq + (float)TT, 1e-5f);
        if (nn < NN)
            outp[((size_t)(b*TT+t)*NN + nn)*AW + h*16 + dd] = f2b(o);
    }
}

extern "C" void kernel_launch(void* const* d_in, const int* in_sizes, int n_in,
                              void* d_out, int out_size, void* d_ws, size_t ws_size,
                              hipStream_t stream)
{
    const float* x     = (const float*)d_in[0];
    const float* graph = (const float*)d_in[1];
    const float* qkv_w = (const float*)d_in[2];
    const float* out_w = (const float*)d_in[3];
    const float* out_b = (const float*)d_in[4];
    const float* pw_w  = (const float*)d_in[5];
    const float* pw_b  = (const float*)d_in[6];
    const float* fc1_w = (const float*)d_in[7];
    const float* fc1_b = (const float*)d_in[8];
    const float* fc2_w = (const float*)d_in[9];
    const float* fc2_b = (const float*)d_in[10];
    const float* ln1g  = (const float*)d_in[11];
    const float* ln1b  = (const float*)d_in[12];
    const float* ln2g  = (const float*)d_in[13];
    const float* ln2b  = (const float*)d_in[14];
    (void)in_sizes; (void)n_in; (void)out_size; (void)ws_size;

    char* ws = (char*)d_ws;
    size_t off = 0;
    __bf16* abuf = (__bf16*)(ws + off); off += (size_t)MROWS*AW*2;      // 244.2 MB
    __bf16* qkvc = (__bf16*)(ws + off); off += (size_t)CROWS*3*DD*2;    // 61.0 MB
    __bf16* gpad = (__bf16*)(ws + off); off += (size_t)TT*NN*KPAD*2;    // 1.1 MB
    __bf16* qkv_wb = (__bf16*)(ws + off); off += (size_t)2*3*DD*DD*2;
    __bf16* wcomb  = (__bf16*)(ws + off); off += (size_t)DD*AW*2;
    __bf16* fc1_wb = (__bf16*)(ws + off); off += (size_t)2*DD*DD*2;
    __bf16* fc2_wb = (__bf16*)(ws + off); off += (size_t)2*DD*DD*2;
    float*  bias_comb = (float*)(ws + off); off += DD*4;                // total ~293 MB

    dim3 blk(256), blk512(512);

    xcopy_kernel<<<dim3(4096), blk, 0, stream>>>(x, abuf);
    prep_misc_kernel<<<dim3(1024), blk, 0, stream>>>(graph, qkv_w, out_w, out_b, pw_w, pw_b,
        fc1_w, fc2_w, gpad, qkv_wb, wcomb, fc1_wb, fc2_wb, bias_comb);
    propagate_kernel<<<dim3(BB*TT, 4), blk, 0, stream>>>(gpad, abuf);

    for (int hop = 0; hop < 2; ++hop) {
        for (int c = 0; c < BB/CHB; ++c) {
            size_t rowoff = (size_t)c*CROWS;
            gemm_kernel<0,false><<<dim3((CROWS+255)/256, 3), blk512, 0, stream>>>(
                abuf + rowoff*AW + hop*DD, (size_t)AW, qkv_wb + (size_t)hop*3*DD*DD, nullptr,
                (void*)qkvc, (size_t)(3*DD), DD, CROWS, nullptr, 0, nullptr, nullptr);
            attn_s_kernel<<<dim3(CHB*TT), blk, 0, stream>>>(
                qkvc, abuf + rowoff*AW + 256 + hop*256);
            attn_t_kernel<<<dim3(CHB, (NN+1)/2), blk, 0, stream>>>(
                qkvc, abuf + rowoff*AW + 384 + hop*256);
        }
    }

    // h = LN(x + abuf@wcomb^T + bias_comb) -> abuf cols 0:128 (bf16), fused epilogue
    gemm_kernel<3,false><<<dim3(MROWS/256, 1), blk512, 0, stream>>>(
        abuf, (size_t)AW, wcomb, bias_comb, (void*)abuf, (size_t)AW, AW, MROWS,
        abuf, (size_t)AW, ln1g, ln1b);
    // ff1 = relu(h @ fc1^T + b1) -> abuf cols 256:512
    gemm_kernel<0,true><<<dim3(MROWS/256, 2), blk512, 0, stream>>>(
        abuf, (size_t)AW, fc1_wb, fc1_b, (void*)(abuf + 256), (size_t)AW, DD, MROWS,
        nullptr, 0, nullptr, nullptr);
    // out = LN(h + ff1 @ fc2^T + b2) -> d_out f32, fused epilogue
    gemm_kernel<4,false><<<dim3(MROWS/256, 1), blk512, 0, stream>>>(
        abuf + 256, (size_t)AW, fc2_wb, fc2_b, d_out, (size_t)DD, 2*DD, MROWS,
        abuf, (size_t)AW, ln2g, ln2b);
}

// Round 7
// 837.889 us; speedup vs baseline: 1.3293x; 1.0309x over previous
//
#include <hip/hip_runtime.h>
#include <hip/hip_bf16.h>

#define BB 64
#define TT 12
#define NN 207
#define DD 128
#define HH 8
#define DH 16
#define MROWS (BB*TT*NN)   // 158976 = 621*256
#define KPAD 224           // graph rows padded to multiple of 32
#define AW 768             // abuf width: [x | xs1 | s0 | t0 | s1 | t1] each 128
#define CHB 32             // batch chunk for qkv/attention
#define CROWS (CHB*TT*NN)  // 79488 rows per chunk

typedef __bf16 bf16x8 __attribute__((ext_vector_type(8)));
typedef float  f32x4  __attribute__((ext_vector_type(4)));

__device__ inline float  b2f(__bf16 v){ return (float)v; }
__device__ inline __bf16 f2b(float v){ return (__bf16)v; }
__device__ inline bf16x8 ldfrag(const __bf16* p){ return *reinterpret_cast<const bf16x8*>(p); }

// async global->LDS, 16B per lane; lds base must be wave-uniform (lane i lands at +16*i)
__device__ inline void gload_lds16(const __bf16* g, __bf16* l){
    __builtin_amdgcn_global_load_lds(
        (const __attribute__((address_space(1))) void*)(g),
        (__attribute__((address_space(3))) void*)(l), 16, 0, 0);
}
__device__ inline int swz(int r){ return (r ^ (r>>2)) & 3; }

// ---------------- x (f32) -> abuf[:,0:128] bf16 ----------------
__global__ __launch_bounds__(256) void xcopy_kernel(const float* __restrict__ x, __bf16* __restrict__ abuf)
{
    int nt = gridDim.x*256;
    for (int gIdx = blockIdx.x*256 + threadIdx.x; gIdx < MROWS*16; gIdx += nt) {
        int row = gIdx >> 4, c8 = (gIdx & 15)*8;
        const float* s = x + (size_t)row*DD + c8;
        f32x4 a = *reinterpret_cast<const f32x4*>(s);
        f32x4 b = *reinterpret_cast<const f32x4*>(s+4);
        bf16x8 r;
        #pragma unroll
        for (int i=0;i<4;i++){ r[i] = f2b(a[i]); r[i+4] = f2b(b[i]); }
        *reinterpret_cast<bf16x8*>(abuf + (size_t)row*AW + c8) = r;
    }
}

// ---------------- misc prep: pad graph + convert weights to bf16 + combined bias ----------------
__global__ __launch_bounds__(256) void prep_misc_kernel(
    const float* __restrict__ graph, const float* __restrict__ qkv_w,
    const float* __restrict__ out_w, const float* __restrict__ out_b,
    const float* __restrict__ pw_w,  const float* __restrict__ pw_b,
    const float* __restrict__ fc1_w, const float* __restrict__ fc2_w,
    __bf16* __restrict__ gpad, __bf16* __restrict__ qkv_wb, __bf16* __restrict__ wcomb,
    __bf16* __restrict__ fc1_wb, __bf16* __restrict__ fc2_wb, float* __restrict__ bias_comb)
{
    int nt = gridDim.x*256;
    int tid = blockIdx.x*256 + threadIdx.x;
    for (int i = tid; i < TT*NN*KPAD; i += nt) {
        int k = i % KPAD, r = i / KPAD;
        gpad[i] = (k < NN) ? f2b(graph[(size_t)r*NN + k]) : f2b(0.f);
    }
    for (int i = tid; i < 2*3*DD*DD; i += nt) qkv_wb[i] = f2b(qkv_w[i]);
    for (int i = tid; i < DD*AW; i += nt) {
        int c = i / AW, j = i % AW;
        float v;
        if      (j < 128) v = pw_w[c*128 + j];
        else if (j < 256) v = pw_w[128*128 + c*128 + (j-128)];
        else if (j < 512) v = out_w[c*256 + (j-256)];
        else              v = out_w[128*256 + c*256 + (j-512)];
        wcomb[i] = f2b(v);
    }
    for (int i = tid; i < 2*DD*DD; i += nt) fc1_wb[i] = f2b(fc1_w[i]);
    for (int i = tid; i < 2*DD*DD; i += nt) fc2_wb[i] = f2b(fc2_w[i]);
    for (int i = tid; i < DD; i += nt)
        bias_comb[i] = pw_b[i] + pw_b[128+i] + out_b[i] + out_b[128+i];
}

// ---------------- propagate: abuf[:,128:256] = graph[t] @ abuf[:,0:128]  per (b,t) ----------------
__global__ __launch_bounds__(256) void propagate_kernel(const __bf16* __restrict__ gp,
    __bf16* __restrict__ abuf)
{
    int bt   = blockIdx.x;          // b*12 + t
    int t    = bt % TT;
    int tile = blockIdx.y;          // 0..3, 64 rows each
    int lane = threadIdx.x & 63, w = threadIdx.x >> 6;
    int lhi = lane >> 4, llo = lane & 15;
    __shared__ __attribute__((aligned(16))) __bf16 XT[DD][40];
    const __bf16* xbt  = abuf + (size_t)bt*NN*AW;     // x cols 0:128
    const __bf16* grow = gp + (size_t)t*NN*KPAD;
    int rowbase = tile*64 + w*16;
    f32x4 acc[8];
    #pragma unroll
    for (int i=0;i<8;i++) acc[i] = (f32x4){0.f,0.f,0.f,0.f};
    int arow = rowbase + llo; if (arow > NN-1) arow = NN-1;
    for (int k0=0; k0<KPAD; k0+=32) {
        __syncthreads();
        for (int kl = (threadIdx.x>>7); kl < 32; kl += 2) {
            int kk = k0 + kl, c = threadIdx.x & 127;
            XT[c][kl] = (kk < NN) ? xbt[(size_t)kk*AW + c] : f2b(0.f);
        }
        __syncthreads();
        bf16x8 a = ldfrag(grow + (size_t)arow*KPAD + k0 + lhi*8);
        #pragma unroll
        for (int cf=0;cf<8;cf++){
            bf16x8 b = *reinterpret_cast<const bf16x8*>(&XT[cf*16+llo][lhi*8]);
            acc[cf] = __builtin_amdgcn_mfma_f32_16x16x32_bf16(a, b, acc[cf], 0,0,0);
        }
    }
    #pragma unroll
    for (int e=0;e<4;e++){
        int row = rowbase + lhi*4 + e;
        if (row < NN) {
            #pragma unroll
            for (int cf=0;cf<8;cf++)
                abuf[((size_t)bt*NN + row)*AW + DD + cf*16 + llo] = f2b(acc[cf][e]);
        }
    }
}

// ---------------- LDS-staged GEMM, 512 threads / 8 waves, block = 256 rows x 128 cols ----------------
// BK=32, 3-deep LDS ring, counted-vmcnt pipeline (T3+T4): loads for tiles t..t+2 stay in
// flight; never drain vmcnt to 0 in the main loop. A-tile [256][32], W-tile [128][32],
// 16B-unit swizzle u^=swz(r) (pre-swizzled global source + swizzled ds_read, rule #21).
// MODE 0: bf16 out (opt RELU).
// MODE 3: out_bf16 = LN(resid + acc + bias) (grid.y==1, NC=128)
// MODE 4: out_f32  = LN(resid + acc + bias) (grid.y==1, NC=128)
template<int MODE, bool RELU>
__global__ __launch_bounds__(512) void gemm_kernel(const __bf16* __restrict__ A, size_t lda,
    const __bf16* __restrict__ W, const float* __restrict__ bias,
    void* out, size_t ldc, int K, int mend,
    const __bf16* __restrict__ resid, size_t ldr,
    const float* __restrict__ lng, const float* __restrict__ lnb)
{
    __shared__ __attribute__((aligned(16))) __bf16 lds[3][12288]; // 3 x (A 8192 | W 4096) = 72KB
    int w = threadIdx.x >> 6, lane = threadIdx.x & 63;
    int lhi = lane >> 4, llo = lane & 15;
    size_t row0 = (size_t)blockIdx.x*256;
    int col0 = blockIdx.y*128;
    int nt = K >> 5;

    // staging slot constants (per thread)
    int sA0 = (w*2+0)*64 + lane, sA1 = (w*2+1)*64 + lane, sW = w*64 + lane;
    int rA0 = sA0>>2, uA0 = sA0&3, rA1 = sA1>>2, uA1 = sA1&3, rW = sW>>2, uW = sW&3;
    long gr0 = (long)row0 + rA0; if (gr0 >= mend) gr0 = mend-1;
    long gr1 = (long)row0 + rA1; if (gr1 >= mend) gr1 = mend-1;
    const __bf16* gA0 = A + (size_t)gr0*lda + ((uA0 ^ swz(rA0))<<3);
    const __bf16* gA1 = A + (size_t)gr1*lda + ((uA1 ^ swz(rA1))<<3);
    const __bf16* gW  = W + (size_t)(col0 + rW)*K + ((uW ^ swz(rW))<<3);
    int slotA0 = (w*2+0)*512 + (sA0&63)*8;   // lane's 16B dest inside a buffer (linear)
    int slotA1 = (w*2+1)*512 + (sA1&63)*8;
    int slotW  = 8192 + w*512 + (sW&63)*8;
    // NOTE: gload_lds16 writes lane-linear from the wave-uniform base; slot math above is
    // equivalent to base + lane*16B. Pass the wave-uniform base (lane 0 slot).
    __bf16* base0 = &lds[0][0];

    // fragment read offsets (per thread, element units within a buffer)
    int aoff[2], woff[8];
    #pragma unroll
    for (int rt=0;rt<2;rt++){
        int rl = w*32 + rt*16 + llo;
        aoff[rt] = rl*32 + ((lhi ^ swz(rl))<<3);
    }
    #pragma unroll
    for (int cf=0;cf<8;cf++){
        int wr = cf*16 + llo;
        woff[cf] = 8192 + wr*32 + ((lhi ^ swz(wr))<<3);
    }

    f32x4 acc[2][8];
    #pragma unroll
    for (int i=0;i<2;i++)
        #pragma unroll
        for (int j=0;j<8;j++) acc[i][j] = (f32x4){0.f,0.f,0.f,0.f};

    #define STAGE(buf, tt) { int k0 = (tt)<<5; __bf16* Lw = base0 + (buf)*12288;           \
        gload_lds16(gA0 + k0, Lw + (w*2+0)*512);                                           \
        gload_lds16(gA1 + k0, Lw + (w*2+1)*512);                                           \
        gload_lds16(gW  + k0, Lw + 8192 + w*512); }

    // prologue: fill the 3-deep ring (9 loads in flight per wave)
    STAGE(0,0); STAGE(1,1); STAGE(2,2);

    int cur = 0;
    for (int t = 0; t < nt; ++t) {
        // counted wait: buf[cur]'s 3 loads are the oldest outstanding
        if (t <= nt-3)      asm volatile("s_waitcnt vmcnt(6)" ::: "memory");
        else if (t == nt-2) asm volatile("s_waitcnt vmcnt(3)" ::: "memory");
        else                asm volatile("s_waitcnt vmcnt(0)" ::: "memory");
        __builtin_amdgcn_s_barrier();          // all waves' buf[cur] DMAs landed
        __builtin_amdgcn_sched_barrier(0);
        const __bf16* Lb = base0 + cur*12288;
        bf16x8 a[2], b[8];
        #pragma unroll
        for (int rt=0;rt<2;rt++) a[rt] = *reinterpret_cast<const bf16x8*>(&Lb[aoff[rt]]);
        #pragma unroll
        for (int cf=0;cf<8;cf++)  b[cf] = *reinterpret_cast<const bf16x8*>(&Lb[woff[cf]]);
        asm volatile("s_waitcnt lgkmcnt(0)" ::: "memory");
        __builtin_amdgcn_sched_barrier(0);
        __builtin_amdgcn_s_barrier();          // all waves done reading buf[cur]
        if (t+3 < nt) STAGE(cur, t+3);         // overwrite; its latency hides under MFMAs
        #pragma unroll
        for (int rt=0;rt<2;rt++)
            #pragma unroll
            for (int cf=0;cf<8;cf++)
                acc[rt][cf] = __builtin_amdgcn_mfma_f32_16x16x32_bf16(a[rt], b[cf], acc[rt][cf], 0,0,0);
        cur = (cur == 2) ? 0 : cur + 1;
    }
    #undef STAGE

    float bv[8];
    #pragma unroll
    for (int cf=0;cf<8;cf++) bv[cf] = bias ? bias[col0 + cf*16 + llo] : 0.f;

    if (MODE == 0) {
        #pragma unroll
        for (int rt=0;rt<2;rt++) {
            #pragma unroll
            for (int e=0;e<4;e++) {
                size_t row = row0 + (size_t)w*32 + rt*16 + lhi*4 + e;
                if ((long)row >= mend) continue;
                #pragma unroll
                for (int cf=0;cf<8;cf++) {
                    float v = acc[rt][cf][e] + bv[cf];
                    if (RELU) v = fmaxf(v, 0.f);
                    ((__bf16*)out)[row*ldc + col0 + cf*16 + llo] = f2b(v);
                }
            }
        }
    } else {
        float g8[8], b8[8];
        #pragma unroll
        for (int cf=0;cf<8;cf++){ int c = cf*16 + llo; g8[cf] = lng[c]; b8[cf] = lnb[c]; }
        #pragma unroll
        for (int rt=0;rt<2;rt++) {
            #pragma unroll
            for (int e=0;e<4;e++) {
                size_t row = row0 + (size_t)w*32 + rt*16 + lhi*4 + e;
                if ((long)row >= mend) continue;
                float vals[8], s = 0.f, ss = 0.f;
                #pragma unroll
                for (int cf=0;cf<8;cf++) {
                    int c = cf*16 + llo;
                    float r = b2f(resid[row*ldr + c]);
                    float v = acc[rt][cf][e] + bv[cf] + r;
                    vals[cf] = v; s += v; ss += v*v;
                }
                #pragma unroll
                for (int o=1;o<16;o<<=1){ s += __shfl_xor(s,o,64); ss += __shfl_xor(ss,o,64); }
                float mean = s * (1.f/DD);
                float var  = ss * (1.f/DD) - mean*mean;
                float rs   = rsqrtf(var + 1e-5f);
                #pragma unroll
                for (int cf=0;cf<8;cf++) {
                    float v = (vals[cf]-mean)*rs*g8[cf] + b8[cf];
                    size_t idx = row*ldc + cf*16 + llo;
                    if (MODE == 3) ((__bf16*)out)[idx] = f2b(v);
                    else           ((float*)out)[idx]  = v;
                }
            }
        }
    }
}

// ---------------- spatial linear attention: one block per chunk-(b,t), all 8 heads ----------------
#define CH 32
__global__ __launch_bounds__(256) void attn_s_kernel(const __bf16* __restrict__ qkv,
                                                     __bf16* __restrict__ outp)
{
    int bt = blockIdx.x;   // chunk-local
    const __bf16* base = qkv + (size_t)bt*NN*384;
    __shared__ __attribute__((aligned(16))) __bf16 rows[CH][392];
    __shared__ float invq[224][8];
    __shared__ float invk_c[CH][8];
    __shared__ float ksum_l[8][16];
    int tid = threadIdx.x;
    int dd = tid & 15, half = (tid >> 4) & 1, h = tid >> 5;
    float kvs_col[16]; float ks = 0.f;
    #pragma unroll
    for (int m=0;m<16;m++) kvs_col[m] = 0.f;

    for (int c0 = 0; c0 < NN; c0 += CH) {
        __syncthreads();
        for (int i = tid; i < CH*48; i += 256) {
            int r = i/48, g = i%48; int n = c0 + r;
            bf16x8 v8 = (bf16x8){};
            if (n < NN) v8 = *reinterpret_cast<const bf16x8*>(base + (size_t)n*384 + g*8);
            *reinterpret_cast<bf16x8*>(&rows[r][g*8]) = v8;
        }
        __syncthreads();
        {
            int r = tid >> 3, hh = tid & 7;
            bf16x8 q0 = *reinterpret_cast<const bf16x8*>(&rows[r][hh*16]);
            bf16x8 q1 = *reinterpret_cast<const bf16x8*>(&rows[r][hh*16+8]);
            bf16x8 k0 = *reinterpret_cast<const bf16x8*>(&rows[r][128+hh*16]);
            bf16x8 k1 = *reinterpret_cast<const bf16x8*>(&rows[r][128+hh*16+8]);
            float sq = 0.f, sk = 0.f;
            #pragma unroll
            for (int m=0;m<8;m++){
                float a0=b2f(q0[m]), a1=b2f(q1[m]); sq += a0*a0 + a1*a1;
                float c0v=b2f(k0[m]), c1=b2f(k1[m]); sk += c0v*c0v + c1*c1;
            }
            invq[c0+r][hh] = 1.f/fmaxf(sqrtf(sq), 1e-12f);
            invk_c[r][hh]  = 1.f/fmaxf(sqrtf(sk), 1e-12f);
        }
        __syncthreads();
        #pragma unroll
        for (int i=0;i<CH/2;i++){
            int r = half*(CH/2) + i;
            float iv = invk_c[r][h];
            bf16x8 k0 = *reinterpret_cast<const bf16x8*>(&rows[r][128+h*16]);
            bf16x8 k1 = *reinterpret_cast<const bf16x8*>(&rows[r][128+h*16+8]);
            float vv  = b2f(rows[r][256+h*16+dd]);
            float kdd = b2f(rows[r][128+h*16+dd]);
            float t2 = iv*vv;
            #pragma unroll
            for (int m=0;m<8;m++){
                kvs_col[m]   += b2f(k0[m])*t2;
                kvs_col[m+8] += b2f(k1[m])*t2;
            }
            ks += kdd*iv;
        }
    }
    #pragma unroll
    for (int m=0;m<16;m++) kvs_col[m] += __shfl_xor(kvs_col[m], 16, 64);
    ks += __shfl_xor(ks, 16, 64);
    ksum_l[h][dd] = ks;
    __syncthreads();
    float ksr[16];
    #pragma unroll
    for (int m=0;m<16;m++) ksr[m] = ksum_l[h][m];

    for (int c0 = 0; c0 < NN; c0 += CH) {
        __syncthreads();
        for (int i = tid; i < CH*48; i += 256) {
            int r = i/48, g = i%48; int n = c0 + r;
            bf16x8 v8 = (bf16x8){};
            if (n < NN) v8 = *reinterpret_cast<const bf16x8*>(base + (size_t)n*384 + g*8);
            *reinterpret_cast<bf16x8*>(&rows[r][g*8]) = v8;
        }
        __syncthreads();
        #pragma unroll
        for (int i=0;i<CH/2;i++){
            int r = half*(CH/2) + i; int n = c0 + r;
            if (n >= NN) continue;
            float iq = invq[n][h];
            bf16x8 q0 = *reinterpret_cast<const bf16x8*>(&rows[r][h*16]);
            bf16x8 q1 = *reinterpret_cast<const bf16x8*>(&rows[r][h*16+8]);
            float num = 0.f, den = 0.f;
            #pragma unroll
            for (int m=0;m<8;m++){
                float qm0 = b2f(q0[m]), qm1 = b2f(q1[m]);
                num += qm0*kvs_col[m] + qm1*kvs_col[m+8];
                den += qm0*ksr[m]     + qm1*ksr[m+8];
            }
            float vv = b2f(rows[r][256+h*16+dd]);
            float o = (num*iq + (float)NN*vv) / fmaxf(den*iq + (float)NN, 1e-5f);
            outp[((size_t)bt*NN + n)*AW + h*16 + dd] = f2b(o);
        }
    }
}

// ---------------- temporal linear attention: one block per chunk-(b, nn-pair) ----------------
__global__ __launch_bounds__(256) void attn_t_kernel(const __bf16* __restrict__ qkv,
                                                     __bf16* __restrict__ outp)
{
    int b = blockIdx.x;    // chunk-local
    int nn0 = blockIdx.y * 2;
    __shared__ __attribute__((aligned(16))) __bf16 rows[TT][2][384];
    __shared__ float invq[2][TT][8], invk2[2][TT][8];
    int tid = threadIdx.x;
    for (int i = tid; i < TT*2*48; i += 256) {
        int t = i / 96, rem = i % 96;
        int nl = rem / 48, g = rem % 48;
        int nn = nn0 + nl;
        bf16x8 v8 = (bf16x8){};
        if (nn < NN) v8 = *reinterpret_cast<const bf16x8*>(qkv + ((size_t)(b*TT+t)*NN + nn)*384 + g*8);
        *reinterpret_cast<bf16x8*>(&rows[t][nl][g*8]) = v8;
    }
    __syncthreads();
    if (tid < 192) {
        int hh = tid & 7, t = (tid >> 3) % TT, nl = tid / 96;
        bf16x8 q0 = *reinterpret_cast<const bf16x8*>(&rows[t][nl][hh*16]);
        bf16x8 q1 = *reinterpret_cast<const bf16x8*>(&rows[t][nl][hh*16+8]);
        bf16x8 k0 = *reinterpret_cast<const bf16x8*>(&rows[t][nl][128+hh*16]);
        bf16x8 k1 = *reinterpret_cast<const bf16x8*>(&rows[t][nl][128+hh*16+8]);
        float sq = 0.f, sk = 0.f;
        #pragma unroll
        for (int m=0;m<8;m++){
            float a0=b2f(q0[m]), a1=b2f(q1[m]); sq += a0*a0 + a1*a1;
            float c0v=b2f(k0[m]), c1=b2f(k1[m]); sk += c0v*c0v + c1*c1;
        }
        invq[nl][t][hh]  = 1.f/fmaxf(sqrtf(sq), 1e-12f);
        invk2[nl][t][hh] = 1.f/fmaxf(sqrtf(sk), 1e-12f);
    }
    __syncthreads();
    int dd = tid & 15, h = (tid >> 4) & 7, nl = tid >> 7;
    int nn = nn0 + nl;
    float kvs_col[16], ksum[16];
    #pragma unroll
    for (int m=0;m<16;m++){ kvs_col[m]=0.f; ksum[m]=0.f; }
    #pragma unroll
    for (int t=0;t<TT;t++){
        float iv = invk2[nl][t][h];
        bf16x8 k0 = *reinterpret_cast<const bf16x8*>(&rows[t][nl][128+h*16]);
        bf16x8 k1 = *reinterpret_cast<const bf16x8*>(&rows[t][nl][128+h*16+8]);
        float vv = b2f(rows[t][nl][256+h*16+dd]);
        float t2 = iv*vv;
        #pragma unroll
        for (int m=0;m<8;m++){
            float km0 = b2f(k0[m]), km1 = b2f(k1[m]);
            kvs_col[m]   += km0*t2;  ksum[m]   += km0*iv;
            kvs_col[m+8] += km1*t2;  ksum[m+8] += km1*iv;
        }
    }
    #pragma unroll
    for (int t=0;t<TT;t++){
        float iq = invq[nl][t][h];
        bf16x8 q0 = *reinterpret_cast<const bf16x8*>(&rows[t][nl][h*16]);
        bf16x8 q1 = *reinterpret_cast<const bf16x8*>(&rows[t][nl][h*16+8]);
        float num = 0.f, den = 0.f;
        #pragma unroll
        for (int m=0;m<8;m++){
            float qm0 = b2f(q0[m]), qm1 = b2f(q1[m]);
            num += qm0*kvs_col[m]  + qm1*kvs_col[m+8];
            den += qm0*ksum[m]     + qm1*ksum[m+8];
        }
        float vv = b2f(rows[t][nl][256+h*16+dd]);
        float o = (num*iq + (float)TT*vv) / fmaxf(den*iq + (float)TT, 1e-5f);
        if (nn < NN)
            outp[((size_t)(b*TT+t)*NN + nn)*AW + h*16 + dd] = f2b(o);
    }
}

extern "C" void kernel_launch(void* const* d_in, const int* in_sizes, int n_in,
                              void* d_out, int out_size, void* d_ws, size_t ws_size,
                              hipStream_t stream)
{
    const float* x     = (const float*)d_in[0];
    const float* graph = (const float*)d_in[1];
    const float* qkv_w = (const float*)d_in[2];
    const float* out_w = (const float*)d_in[3];
    const float* out_b = (const float*)d_in[4];
    const float* pw_w  = (const float*)d_in[5];
    const float* pw_b  = (const float*)d_in[6];
    const float* fc1_w = (const float*)d_in[7];
    const float* fc1_b = (const float*)d_in[8];
    const float* fc2_w = (const float*)d_in[9];
    const float* fc2_b = (const float*)d_in[10];
    const float* ln1g  = (const float*)d_in[11];
    const float* ln1b  = (const float*)d_in[12];
    const float* ln2g  = (const float*)d_in[13];
    const float* ln2b  = (const float*)d_in[14];
    (void)in_sizes; (void)n_in; (void)out_size; (void)ws_size;

    char* ws = (char*)d_ws;
    size_t off = 0;
    __bf16* abuf = (__bf16*)(ws + off); off += (size_t)MROWS*AW*2;      // 244.2 MB
    __bf16* qkvc = (__bf16*)(ws + off); off += (size_t)CROWS*3*DD*2;    // 61.0 MB
    __bf16* gpad = (__bf16*)(ws + off); off += (size_t)TT*NN*KPAD*2;    // 1.1 MB
    __bf16* qkv_wb = (__bf16*)(ws + off); off += (size_t)2*3*DD*DD*2;
    __bf16* wcomb  = (__bf16*)(ws + off); off += (size_t)DD*AW*2;
    __bf16* fc1_wb = (__bf16*)(ws + off); off += (size_t)2*DD*DD*2;
    __bf16* fc2_wb = (__bf16*)(ws + off); off += (size_t)2*DD*DD*2;
    float*  bias_comb = (float*)(ws + off); off += DD*4;                // total ~293 MB

    dim3 blk(256), blk512(512);

    xcopy_kernel<<<dim3(4096), blk, 0, stream>>>(x, abuf);
    prep_misc_kernel<<<dim3(1024), blk, 0, stream>>>(graph, qkv_w, out_w, out_b, pw_w, pw_b,
        fc1_w, fc2_w, gpad, qkv_wb, wcomb, fc1_wb, fc2_wb, bias_comb);
    propagate_kernel<<<dim3(BB*TT, 4), blk, 0, stream>>>(gpad, abuf);

    for (int hop = 0; hop < 2; ++hop) {
        for (int c = 0; c < BB/CHB; ++c) {
            size_t rowoff = (size_t)c*CROWS;
            gemm_kernel<0,false><<<dim3((CROWS+255)/256, 3), blk512, 0, stream>>>(
                abuf + rowoff*AW + hop*DD, (size_t)AW, qkv_wb + (size_t)hop*3*DD*DD, nullptr,
                (void*)qkvc, (size_t)(3*DD), DD, CROWS, nullptr, 0, nullptr, nullptr);
            attn_s_kernel<<<dim3(CHB*TT), blk, 0, stream>>>(
                qkvc, abuf + rowoff*AW + 256 + hop*256);
            attn_t_kernel<<<dim3(CHB, (NN+1)/2), blk, 0, stream>>>(
                qkvc, abuf + rowoff*AW + 384 + hop*256);
        }
    }

    // h = LN(x + abuf@wcomb^T + bias_comb) -> abuf cols 0:128 (bf16), fused epilogue
    gemm_kernel<3,false><<<dim3(MROWS/256, 1), blk512, 0, stream>>>(
        abuf, (size_t)AW, wcomb, bias_comb, (void*)abuf, (size_t)AW, AW, MROWS,
        abuf, (size_t)AW, ln1g, ln1b);
    // ff1 = relu(h @ fc1^T + b1) -> abuf cols 256:512
    gemm_kernel<0,true><<<dim3(MROWS/256, 2), blk512, 0, stream>>>(
        abuf, (size_t)AW, fc1_wb, fc1_b, (void*)(abuf + 256), (size_t)AW, DD, MROWS,
        nullptr, 0, nullptr, nullptr);
    // out = LN(h + ff1 @ fc2^T + b2) -> d_out f32, fused epilogue
    gemm_kernel<4,false><<<dim3(MROWS/256, 1), blk512, 0, stream>>>(
        abuf + 256, (size_t)AW, fc2_wb, fc2_b, d_out, (size_t)DD, 2*DD, MROWS,
        abuf, (size_t)AW, ln2g, ln2b);
}